// Round 12
// baseline (330.199 us; speedup 1.0000x reference)
//
#include <hip/hip_runtime.h>
#include <cstdint>

// MultiHeadAttention: B=4, S=2048, D=1024, H=16, HD=64. fp32 in/out, bf16 MFMA compute.
// R21: revert to R18 composition (best e2e 262.6); attn keeps R13 shape (8w x 32 q-rows,
// Q-tile 256, grid 512) but V is read DIRECT FROM GLOBAL (L2-resident; vt rows give the
// PV B-frag as 8 contiguous bf16) -- sV staging + 8 ds_read_b128/iter removed from the
// serial chain; LDS 64->48KB. R20's Q-tile-128 occupancy push regressed (halved
// per-wave work) and is reverted. qkv_384 (R18), gemm_bt, cvt_all unchanged.

#define B_ 4
#define S_ 2048
#define D_ 1024
#define H_ 16
#define HD_ 64
#define QKV_N 3072
#define QK_LD 2048  // q|k buffer row stride (V lives in vt)
#define SCALE_Q 0.18033688011111772f  // 0.125 * log2(e)

typedef __bf16 bf16x8 __attribute__((ext_vector_type(8)));
typedef __bf16 bf16x2 __attribute__((ext_vector_type(2)));
typedef float f32x4 __attribute__((ext_vector_type(4)));
typedef short short8 __attribute__((ext_vector_type(8)));

__device__ __forceinline__ unsigned short f2bf(float f) {
  unsigned int u = __builtin_bit_cast(unsigned int, f);
  u = (u + 0x7FFFu + ((u >> 16) & 1u)) >> 16;  // RNE
  return (unsigned short)u;
}

__device__ __forceinline__ unsigned int pkbf(float a, float b) {
  bf16x2 v;
  v.x = (__bf16)a;
  v.y = (__bf16)b;
  return __builtin_bit_cast(unsigned int, v);
}

__device__ __forceinline__ void gload16(const void* g, void* l) {
  __builtin_amdgcn_global_load_lds(
      (const __attribute__((address_space(1))) void*)g,
      (__attribute__((address_space(3))) void*)l, 16, 0, 0);
}

// Fused elementwise front-end.
__global__ __launch_bounds__(256) void cvt_all(
    const float* __restrict__ x, const float* __restrict__ w0, const float* __restrict__ w1,
    const float* __restrict__ w2, const float* __restrict__ w3,
    const float* __restrict__ bq, const float* __restrict__ bk, const float* __restrict__ bv,
    unsigned short* __restrict__ xb, unsigned short* __restrict__ wcat,
    float* __restrict__ bcat) {
  const int blk = blockIdx.x;
  const int t = threadIdx.x;
  if (blk < 4096) {
    size_t i = (size_t)blk * 256 + t;
    const float4* p = (const float4*)x + i * 2;
    float4 a = p[0], b = p[1];
    unsigned short o[8] = {f2bf(a.x), f2bf(a.y), f2bf(a.z), f2bf(a.w),
                           f2bf(b.x), f2bf(b.y), f2bf(b.z), f2bf(b.w)};
    *(uint4*)(xb + i * 8) = *(const uint4*)o;
  } else if (blk < 6144) {
    int y = (blk - 4096) >> 9;
    const float* src = (y == 0) ? w0 : (y == 1) ? w1 : (y == 2) ? w2 : w3;
    float s = (y == 0) ? SCALE_Q : 1.0f;
    size_t i = (size_t)((blk - 4096) & 511) * 256 + t;
    const float4* p = (const float4*)src + i * 2;
    float4 a = p[0], b = p[1];
    unsigned short o[8] = {f2bf(a.x * s), f2bf(a.y * s), f2bf(a.z * s), f2bf(a.w * s),
                           f2bf(b.x * s), f2bf(b.y * s), f2bf(b.z * s), f2bf(b.w * s)};
    *(uint4*)(wcat + (size_t)y * 1048576 + i * 8) = *(const uint4*)o;
  } else {
    for (int i = t; i < 3072; i += 256) {
      float v = (i < 1024) ? bq[i] * SCALE_Q : (i < 2048) ? bk[i - 1024] : bv[i - 2048];
      bcat[i] = v;
    }
  }
}

#define SBAR() __builtin_amdgcn_sched_barrier(0)
#define BARRIER()                      \
  do {                                 \
    SBAR();                            \
    __builtin_amdgcn_s_barrier();      \
    SBAR();                            \
  } while (0)
#define WAITLGKM()                                      \
  do {                                                  \
    asm volatile("s_waitcnt lgkmcnt(0)" ::: "memory");  \
    SBAR();                                             \
  } while (0)

// ---------------- QKV GEMM: 128x384, 4-phase, 512 tiles = 2 exact rounds (R18) ----------------
__device__ __forceinline__ void ld_af2(const unsigned short* s, int rowbase, int quad,
                                       int sw, bf16x8 af[2][2]) {
#pragma unroll
  for (int mi2 = 0; mi2 < 2; ++mi2) {
    int row = rowbase + mi2 * 16;
#pragma unroll
    for (int kk = 0; kk < 2; ++kk)
      af[mi2][kk] = *(const bf16x8*)&s[row * 64 + ((((kk << 2) + quad) ^ sw) << 3)];
  }
}

__device__ __forceinline__ void ld_bf3(const unsigned short* s, int rowbase, int quad,
                                       int sw, bf16x8 bf[3][2]) {
#pragma unroll
  for (int ni2 = 0; ni2 < 3; ++ni2) {
    int row = rowbase + ni2 * 16;
#pragma unroll
    for (int kk = 0; kk < 2; ++kk)
      bf[ni2][kk] = *(const bf16x8*)&s[row * 64 + ((((kk << 2) + quad) ^ sw) << 3)];
  }
}

#define MMQ(qm, half, BF)                                                                \
  _Pragma("unroll") for (int mi2 = 0; mi2 < 2; ++mi2)                                    \
  _Pragma("unroll") for (int ni2 = 0; ni2 < 3; ++ni2)                                    \
  _Pragma("unroll") for (int kk = 0; kk < 2; ++kk)                                       \
      acc[(qm) * 2 + mi2][(half) * 3 + ni2] = __builtin_amdgcn_mfma_f32_16x16x32_bf16(   \
          af[mi2][kk], BF[ni2][kk], acc[(qm) * 2 + mi2][(half) * 3 + ni2], 0, 0, 0);

__global__ __launch_bounds__(512, 2) void gemm_qkv_384(
    const unsigned short* __restrict__ A, const unsigned short* __restrict__ W,
    const float* __restrict__ bias, unsigned short* __restrict__ qk,
    unsigned short* __restrict__ vt) {
  __shared__ __attribute__((aligned(16))) unsigned short sA[2][128 * 64];  // 32KB
  __shared__ __attribute__((aligned(16))) unsigned short sB[2][384 * 64];  // 96KB

  const int t = threadIdx.x;
  const int lane = t & 63;
  const int w = t >> 6;
  const int lm = lane & 15;
  const int quad = lane >> 4;
  const int sw = lm & 7;
  const int wm = (w >> 2) * 64;   // 2 M-groups of 64
  const int wn = (w & 3) * 96;    // 4 N-groups of 96

  const int bid = blockIdx.x;
  const int xcd = bid & 7, lin = bid >> 3;
  const int mt = xcd * 8 + (lin & 7);   // 0..63
  const int nt = lin >> 3;              // 0..7
  const int m0 = mt * 128, n0 = nt * 384;
  const int K = 1024;

  const int srow = t >> 3;
  const int scol = ((t & 7) ^ ((t >> 3) & 7)) << 3;
  const unsigned short* Ab = A + ((size_t)m0 + srow) * K + scol;
  const unsigned short* Wb = W + ((size_t)n0 + srow) * K + scol;

#define QSTG_A(bb, q, kt) gload16(Ab + (size_t)((q) * 64) * K + (kt), &sA[bb][(q) * 4096 + w * 512])
#define QSTG_B(bb, q, kt) gload16(Wb + (size_t)((q) * 64) * K + (kt), &sB[bb][(q) * 4096 + w * 512])

  QSTG_A(0, 0, 0); QSTG_A(0, 1, 0);
  QSTG_B(0, 0, 0); QSTG_B(0, 1, 0); QSTG_B(0, 2, 0);
  QSTG_B(0, 3, 0); QSTG_B(0, 4, 0); QSTG_B(0, 5, 0);
  QSTG_B(1, 0, 64); QSTG_B(1, 1, 64);
  QSTG_A(1, 0, 64); QSTG_A(1, 1, 64);
  QSTG_B(1, 2, 64); QSTG_B(1, 3, 64);
  asm volatile("s_waitcnt vmcnt(6)" ::: "memory");
  BARRIER();

  f32x4 acc[4][6] = {};
  bf16x8 af[2][2], bf0[3][2], bf1[3][2];

#define QGROUP(c, kn1, kn2)                                                           \
  do {                                                                                \
    ld_af2(sA[c], wm + lm, quad, sw, af);                                             \
    ld_bf3(sB[c], wn + lm, quad, sw, bf0);                                            \
    QSTG_B(c ^ 1, 4, kn1);                                                            \
    QSTG_B(c ^ 1, 5, kn1);                                                            \
    BARRIER(); WAITLGKM();                                                            \
    __builtin_amdgcn_s_setprio(1); MMQ(0, 0, bf0); __builtin_amdgcn_s_setprio(0);     \
    BARRIER();                                                                        \
    ld_bf3(sB[c], wn + 48 + lm, quad, sw, bf1);                                       \
    BARRIER(); WAITLGKM();                                                            \
    __builtin_amdgcn_s_setprio(1); MMQ(0, 1, bf1); __builtin_amdgcn_s_setprio(0);     \
    BARRIER();                                                                        \
    ld_af2(sA[c], wm + 32 + lm, quad, sw, af);                                        \
    QSTG_B(c, 0, kn2);                                                                \
    QSTG_B(c, 1, kn2);                                                                \
    BARRIER(); WAITLGKM();                                                            \
    __builtin_amdgcn_s_setprio(1); MMQ(1, 0, bf0); __builtin_amdgcn_s_setprio(0);     \
    BARRIER();                                                                        \
    QSTG_A(c, 0, kn2);                                                                \
    QSTG_A(c, 1, kn2);                                                                \
    QSTG_B(c, 2, kn2);                                                                \
    QSTG_B(c, 3, kn2);                                                                \
    asm volatile("s_waitcnt vmcnt(6)" ::: "memory");                                  \
    BARRIER();                                                                        \
    __builtin_amdgcn_s_setprio(1); MMQ(1, 1, bf1); __builtin_amdgcn_s_setprio(0);     \
    BARRIER();                                                                        \
  } while (0)

  for (int kt = 0; kt < K; kt += 128) {
    const int kn1a = kt + 64;
    const int kn2a = (kt + 128 < K) ? kt + 128 : K - 64;
    const int kn1b = kn2a;
    const int kn2b = (kt + 192 < K) ? kt + 192 : K - 64;
    QGROUP(0, kn1a, kn2a);
    QGROUP(1, kn1b, kn2b);
  }

  asm volatile("s_waitcnt vmcnt(0)" ::: "memory");

#pragma unroll
  for (int mi = 0; mi < 4; ++mi) {
    const int rbase = m0 + wm + mi * 16 + quad * 4;
#pragma unroll
    for (int ni = 0; ni < 6; ++ni) {
      const int col = n0 + wn + ni * 16 + lm;
      const float bv = bias[col];
      float v0 = acc[mi][ni][0] + bv, v1 = acc[mi][ni][1] + bv;
      float v2 = acc[mi][ni][2] + bv, v3 = acc[mi][ni][3] + bv;
      if (col < 2048) {
        qk[(size_t)(rbase + 0) * QK_LD + col] = f2bf(v0);
        qk[(size_t)(rbase + 1) * QK_LD + col] = f2bf(v1);
        qk[(size_t)(rbase + 2) * QK_LD + col] = f2bf(v2);
        qk[(size_t)(rbase + 3) * QK_LD + col] = f2bf(v3);
      } else {  // V: write transposed, 4 consecutive tokens -> one b64
        int c2 = col - 2048;
        int bh = (m0 >> 11) * 16 + (c2 >> 6);
        int hd = c2 & 63;
        int sbase = rbase & 2047;
        uint2 pk = {pkbf(v0, v1), pkbf(v2, v3)};
        *(uint2*)(vt + (size_t)bh * (HD_ * S_) + (size_t)hd * S_ + sbase) = pk;
      }
    }
  }
}

// ---------------- 128x128 gemm (out-proj; proven ~30us @ N=1024) ----------------
__global__ __launch_bounds__(256) void gemm_bt(
    const unsigned short* __restrict__ A, const unsigned short* __restrict__ W,
    const float* __restrict__ bias, void* __restrict__ Cout,
    unsigned short* __restrict__ vt, int M, int N, int K, int mode) {
  __shared__ __attribute__((aligned(16))) unsigned short sA[128 * 32];
  __shared__ __attribute__((aligned(16))) unsigned short sB[128 * 32];
  const int t = threadIdx.x;
  const int lane = t & 63;
  const int w = t >> 6;
  const int lm = lane & 15;
  const int quad = lane >> 4;
  const int m0 = blockIdx.x * 128;
  const int n0 = blockIdx.y * 128;
  const int wm = (w & 1) * 64;
  const int wn = (w >> 1) * 64;

  const int off0 = t * 8, off1 = t * 8 + 2048;
  const int ar0 = off0 >> 5, ac0 = (((off0 >> 3) & 3) ^ ((ar0 >> 1) & 3)) * 8;
  const int ar1 = off1 >> 5, ac1 = (((off1 >> 3) & 3) ^ ((ar1 >> 1) & 3)) * 8;
  const unsigned short* Ag0 = A + (size_t)(m0 + ar0) * K + ac0;
  const unsigned short* Ag1 = A + (size_t)(m0 + ar1) * K + ac1;
  const unsigned short* Wg0 = W + (size_t)(n0 + ar0) * K + ac0;
  const unsigned short* Wg1 = W + (size_t)(n0 + ar1) * K + ac1;
  unsigned short* sA0 = &sA[w * 512];
  unsigned short* sA1 = &sA[2048 + w * 512];
  unsigned short* sB0 = &sB[w * 512];
  unsigned short* sB1 = &sB[2048 + w * 512];

  f32x4 acc[4][4] = {};

  for (int kt = 0; kt < K; kt += 32) {
    gload16(Ag0 + kt, sA0);
    gload16(Ag1 + kt, sA1);
    gload16(Wg0 + kt, sB0);
    gload16(Wg1 + kt, sB1);
    __syncthreads();
    bf16x8 af[4], bf[4];
#pragma unroll
    for (int mi = 0; mi < 4; ++mi) {
      int row = wm + mi * 16 + lm;
      af[mi] = *(const bf16x8*)&sA[row * 32 + ((quad ^ ((row >> 1) & 3)) << 3)];
    }
#pragma unroll
    for (int ni = 0; ni < 4; ++ni) {
      int row = wn + ni * 16 + lm;
      bf[ni] = *(const bf16x8*)&sB[row * 32 + ((quad ^ ((row >> 1) & 3)) << 3)];
    }
#pragma unroll
    for (int mi = 0; mi < 4; ++mi)
#pragma unroll
      for (int ni = 0; ni < 4; ++ni)
        acc[mi][ni] = __builtin_amdgcn_mfma_f32_16x16x32_bf16(af[mi], bf[ni], acc[mi][ni], 0, 0, 0);
    __syncthreads();
  }

#pragma unroll
  for (int mi = 0; mi < 4; ++mi)
#pragma unroll
    for (int ni = 0; ni < 4; ++ni) {
      int col = n0 + wn + ni * 16 + lm;
      float bv = bias[col];
      float v0 = acc[mi][ni][0] + bv, v1 = acc[mi][ni][1] + bv;
      float v2 = acc[mi][ni][2] + bv, v3 = acc[mi][ni][3] + bv;
      int rbase = m0 + wm + mi * 16 + quad * 4;
      if (mode == 0) {
        float* op = (float*)Cout;
        op[(size_t)(rbase + 0) * N + col] = v0;
        op[(size_t)(rbase + 1) * N + col] = v1;
        op[(size_t)(rbase + 2) * N + col] = v2;
        op[(size_t)(rbase + 3) * N + col] = v3;
      } else if (col < 2048) {
        unsigned short* op = (unsigned short*)Cout;
        op[(size_t)(rbase + 0) * QK_LD + col] = f2bf(v0);
        op[(size_t)(rbase + 1) * QK_LD + col] = f2bf(v1);
        op[(size_t)(rbase + 2) * QK_LD + col] = f2bf(v2);
        op[(size_t)(rbase + 3) * QK_LD + col] = f2bf(v3);
      } else {
        int c = col - 2048;
        int bh = (m0 >> 11) * 16 + (c >> 6);
        int hd = c & 63;
        int sbase = (rbase & 2047);
        uint2 pk = {pkbf(v0, v1), pkbf(v2, v3)};
        *(uint2*)(vt + (size_t)bh * (HD_ * S_) + (size_t)hd * S_ + sbase) = pk;
      }
    }
}

// ---------------- flash attention (R21: R13 shape + V direct from global/L2) ----------------
// Block = (b,h) x 256 Q-rows; 512 threads = 8 waves, 32 q-rows/wave. Grid 512,
// bh = blk&63 (same-head blocks -> same XCD -> K/V L2-local).
// K staged in LDS (dbuf, prefetch-ahead); V read directly from vt[bh][hd][S]: the PV
// B-frag for lane (lm,quad) is 8 CONTIGUOUS bf16 at vt[nf*16+lm][n0+kc*32+quad*8] --
// one b128 global load, issued at top of iter so L2 latency hides under QK+softmax.
// Removes sV staging + 8 ds_read_b128/iter from the serial chain. LDS 48KB.
__global__ __launch_bounds__(512, 4) void attn_kernel(
    const unsigned short* __restrict__ qk, const unsigned short* __restrict__ vt,
    unsigned short* __restrict__ ab) {
  __shared__ __attribute__((aligned(16))) unsigned short sK[2][64 * 64];  // 16KB
  __shared__ __attribute__((aligned(16))) unsigned short sP[8][32 * 64];  // 4KB/wave

  const int t = threadIdx.x;
  const int lane = t & 63;
  const int w = t >> 6;  // 0..7
  const int lm = lane & 15;
  const int quad = lane >> 4;
  const int bh = blockIdx.x & 63;
  const int b = bh >> 4, h = bh & 15;
  const int q0 = (blockIdx.x >> 6) * 256;

  const unsigned short* qg = qk + (size_t)b * S_ * QK_LD + h * HD_;
  const unsigned short* kg = qg + 1024;
  const unsigned short* vg = vt + (size_t)bh * HD_ * S_;

  const int r0 = t >> 3;
  const int c0 = ((t & 7) ^ (r0 & 7)) * 8;

  gload16(kg + (size_t)r0 * QK_LD + c0, &sK[0][w * 512]);

  bf16x8 qf[2][2];
#pragma unroll
  for (int mi = 0; mi < 2; ++mi) {
    int row = q0 + w * 32 + mi * 16 + lm;
#pragma unroll
    for (int kc = 0; kc < 2; ++kc)
      qf[mi][kc] = *(const bf16x8*)(qg + (size_t)row * QK_LD + kc * 32 + quad * 8);
  }
  __syncthreads();  // K0 staged

  unsigned short* sPw = sP[w];
  const bf16x8 ones = __builtin_bit_cast(bf16x8, (short8)(short)0x3F80);  // 1.0 bf16
  f32x4 o[2][4] = {};
  f32x4 Lacc[2] = {};

  for (int n0 = 0; n0 < S_; n0 += 64) {
    const int cur = (n0 >> 6) & 1, nxt = cur ^ 1;

    // V fragments for THIS tile, direct from global (L2-resident). Issued first:
    // ~300cy L2 latency hides under K-prefetch + QK MFMA + softmax below.
    bf16x8 vf[2][4];
#pragma unroll
    for (int kc = 0; kc < 2; ++kc)
#pragma unroll
      for (int nf = 0; nf < 4; ++nf)
        vf[kc][nf] = *(const bf16x8*)(vg + (size_t)(nf * 16 + lm) * S_ + n0 + kc * 32 + quad * 8);

    if (n0 + 64 < S_) {  // prefetch next K tile (wave-uniform)
      gload16(kg + (size_t)(n0 + 64 + r0) * QK_LD + c0, &sK[nxt][w * 512]);
    }

    // S^T[key][q-row]: A = K (lane = key), B = Q (lane = q-row).
    f32x4 s[2][4] = {};
#pragma unroll
    for (int kc = 0; kc < 2; ++kc)
#pragma unroll
      for (int nb = 0; nb < 4; ++nb) {
        int row = nb * 16 + lm;
        bf16x8 kf = *(const bf16x8*)&sK[cur][row * 64 + (((kc * 4 + quad) ^ (row & 7)) << 3)];
#pragma unroll
        for (int mi = 0; mi < 2; ++mi)
          s[mi][nb] = __builtin_amdgcn_mfma_f32_16x16x32_bf16(kf, qf[mi][kc], s[mi][nb], 0, 0, 0);
      }

    // exp2 + pk-cvt 4 consecutive keys -> one ds_write_b64 per (mi, nb).
#pragma unroll
    for (int mi = 0; mi < 2; ++mi) {
      int prow = mi * 16 + lm;
      char* rowp = (char*)sPw + prow * 128;
#pragma unroll
      for (int nb = 0; nb < 4; ++nb) {
        const f32x4& sv = s[mi][nb];
        uint2 pk = {pkbf(__builtin_amdgcn_exp2f(sv[0]), __builtin_amdgcn_exp2f(sv[1])),
                    pkbf(__builtin_amdgcn_exp2f(sv[2]), __builtin_amdgcn_exp2f(sv[3]))};
        int c16 = (nb * 2 + (quad >> 1)) ^ (prow & 7);
        *(uint2*)(rowp + (c16 << 4) + ((quad & 1) << 3)) = pk;
      }
    }

    // PV + L. pf from sP; vf already in registers (global loads above).
#pragma unroll
    for (int kc = 0; kc < 2; ++kc) {
      bf16x8 pf[2];
#pragma unroll
      for (int mi = 0; mi < 2; ++mi) {
        int prow = mi * 16 + lm;
        pf[mi] = *(const bf16x8*)&sPw[prow * 64 + (((kc * 4 + quad) ^ (prow & 7)) << 3)];
        Lacc[mi] = __builtin_amdgcn_mfma_f32_16x16x32_bf16(pf[mi], ones, Lacc[mi], 0, 0, 0);
      }
#pragma unroll
      for (int nf = 0; nf < 4; ++nf) {
#pragma unroll
        for (int mi = 0; mi < 2; ++mi)
          o[mi][nf] = __builtin_amdgcn_mfma_f32_16x16x32_bf16(pf[mi], vf[kc][nf], o[mi][nf], 0, 0, 0);
      }
    }
    __syncthreads();  // publishes K prefetch + protects sK[cur] reuse
  }

#pragma unroll
  for (int mi = 0; mi < 2; ++mi)
#pragma unroll
    for (int r = 0; r < 4; ++r) {
      float rinv = 1.0f / Lacc[mi][r];
      int row = q0 + w * 32 + mi * 16 + quad * 4 + r;
#pragma unroll
      for (int nf = 0; nf < 4; ++nf) {
        int col = h * HD_ + nf * 16 + lm;
        ab[(size_t)(b * S_ + row) * D_ + col] = f2bf(o[mi][nf][r] * rinv);
      }
    }
}

extern "C" void kernel_launch(void* const* d_in, const int* in_sizes, int n_in,
                              void* d_out, int out_size, void* d_ws, size_t ws_size,
                              hipStream_t stream) {
  const float* x = (const float*)d_in[0];
  const float* Wq = (const float*)d_in[1];
  const float* bq = (const float*)d_in[2];
  const float* Wk = (const float*)d_in[3];
  const float* bk = (const float*)d_in[4];
  const float* Wv = (const float*)d_in[5];
  const float* bv = (const float*)d_in[6];
  const float* Wo = (const float*)d_in[7];
  const float* bo = (const float*)d_in[8];
  float* out = (float*)d_out;

  const size_t E = (size_t)B_ * S_ * D_;   // 8388608
  const size_t WE = (size_t)D_ * D_;       // 1048576
  unsigned short* xb = (unsigned short*)d_ws;
  unsigned short* wcat = xb + E;
  unsigned short* wob = wcat + 3 * WE;
  float* bcat = (float*)(wcat + 4 * WE);
  unsigned short* qkb = (unsigned short*)(bcat + 4096);
  unsigned short* vtb = qkb + (size_t)B_ * S_ * QK_LD;
  unsigned short* abuf = xb;  // reuse: x consumed by QKV gemm before attention writes

  cvt_all<<<dim3(6145), 256, 0, stream>>>(x, Wq, Wk, Wv, Wo, bq, bk, bv, xb, wcat, bcat);

  gemm_qkv_384<<<dim3(512), 512, 0, stream>>>(xb, wcat, bcat, qkb, vtb);
  attn_kernel<<<dim3(512), 512, 0, stream>>>(qkb, vtb, abuf);
  gemm_bt<<<dim3((B_ * S_) / 128, D_ / 128), 256, 0, stream>>>(
      abuf, wob, bo, out, nullptr, B_ * S_, D_, D_, 0);
}

// Round 13
// 258.846 us; speedup vs baseline: 1.2757x; 1.2757x over previous
//
#include <hip/hip_runtime.h>
#include <cstdint>

// MultiHeadAttention: B=4, S=2048, D=1024, H=16, HD=64. fp32 in/out, bf16 MFMA compute.
// R22 = exact R18 composition (best measured e2e: 262.6us), restored after R21's
// V-direct-from-global regression (147us attn: 16-cacheline gather per vf load put
// 8 L2-latency chains INTO the serial path). Components: cvt_all (fused front-end),
// gemm_qkv_384 (4-phase, 512 tiles = 2 exact rounds), attn R13 (8w x 32 q-rows,
// sK+sV LDS dbuf, 2 blocks/CU), gemm_bt out-proj (128^2 high-occupancy).

#define B_ 4
#define S_ 2048
#define D_ 1024
#define H_ 16
#define HD_ 64
#define QKV_N 3072
#define QK_LD 2048  // q|k buffer row stride (V lives in vt)
#define SCALE_Q 0.18033688011111772f  // 0.125 * log2(e)

typedef __bf16 bf16x8 __attribute__((ext_vector_type(8)));
typedef __bf16 bf16x2 __attribute__((ext_vector_type(2)));
typedef float f32x4 __attribute__((ext_vector_type(4)));
typedef short short8 __attribute__((ext_vector_type(8)));

__device__ __forceinline__ unsigned short f2bf(float f) {
  unsigned int u = __builtin_bit_cast(unsigned int, f);
  u = (u + 0x7FFFu + ((u >> 16) & 1u)) >> 16;  // RNE
  return (unsigned short)u;
}

__device__ __forceinline__ unsigned int pkbf(float a, float b) {
  bf16x2 v;
  v.x = (__bf16)a;
  v.y = (__bf16)b;
  return __builtin_bit_cast(unsigned int, v);
}

__device__ __forceinline__ void gload16(const void* g, void* l) {
  __builtin_amdgcn_global_load_lds(
      (const __attribute__((address_space(1))) void*)g,
      (__attribute__((address_space(3))) void*)l, 16, 0, 0);
}

// Fused elementwise front-end.
__global__ __launch_bounds__(256) void cvt_all(
    const float* __restrict__ x, const float* __restrict__ w0, const float* __restrict__ w1,
    const float* __restrict__ w2, const float* __restrict__ w3,
    const float* __restrict__ bq, const float* __restrict__ bk, const float* __restrict__ bv,
    unsigned short* __restrict__ xb, unsigned short* __restrict__ wcat,
    float* __restrict__ bcat) {
  const int blk = blockIdx.x;
  const int t = threadIdx.x;
  if (blk < 4096) {
    size_t i = (size_t)blk * 256 + t;
    const float4* p = (const float4*)x + i * 2;
    float4 a = p[0], b = p[1];
    unsigned short o[8] = {f2bf(a.x), f2bf(a.y), f2bf(a.z), f2bf(a.w),
                           f2bf(b.x), f2bf(b.y), f2bf(b.z), f2bf(b.w)};
    *(uint4*)(xb + i * 8) = *(const uint4*)o;
  } else if (blk < 6144) {
    int y = (blk - 4096) >> 9;
    const float* src = (y == 0) ? w0 : (y == 1) ? w1 : (y == 2) ? w2 : w3;
    float s = (y == 0) ? SCALE_Q : 1.0f;
    size_t i = (size_t)((blk - 4096) & 511) * 256 + t;
    const float4* p = (const float4*)src + i * 2;
    float4 a = p[0], b = p[1];
    unsigned short o[8] = {f2bf(a.x * s), f2bf(a.y * s), f2bf(a.z * s), f2bf(a.w * s),
                           f2bf(b.x * s), f2bf(b.y * s), f2bf(b.z * s), f2bf(b.w * s)};
    *(uint4*)(wcat + (size_t)y * 1048576 + i * 8) = *(const uint4*)o;
  } else {
    for (int i = t; i < 3072; i += 256) {
      float v = (i < 1024) ? bq[i] * SCALE_Q : (i < 2048) ? bk[i - 1024] : bv[i - 2048];
      bcat[i] = v;
    }
  }
}

#define SBAR() __builtin_amdgcn_sched_barrier(0)
#define BARRIER()                      \
  do {                                 \
    SBAR();                            \
    __builtin_amdgcn_s_barrier();      \
    SBAR();                            \
  } while (0)
#define WAITLGKM()                                      \
  do {                                                  \
    asm volatile("s_waitcnt lgkmcnt(0)" ::: "memory");  \
    SBAR();                                             \
  } while (0)

// ---------------- QKV GEMM: 128x384, 4-phase, 512 tiles = 2 exact rounds (R18) ----------------
__device__ __forceinline__ void ld_af2(const unsigned short* s, int rowbase, int quad,
                                       int sw, bf16x8 af[2][2]) {
#pragma unroll
  for (int mi2 = 0; mi2 < 2; ++mi2) {
    int row = rowbase + mi2 * 16;
#pragma unroll
    for (int kk = 0; kk < 2; ++kk)
      af[mi2][kk] = *(const bf16x8*)&s[row * 64 + ((((kk << 2) + quad) ^ sw) << 3)];
  }
}

__device__ __forceinline__ void ld_bf3(const unsigned short* s, int rowbase, int quad,
                                       int sw, bf16x8 bf[3][2]) {
#pragma unroll
  for (int ni2 = 0; ni2 < 3; ++ni2) {
    int row = rowbase + ni2 * 16;
#pragma unroll
    for (int kk = 0; kk < 2; ++kk)
      bf[ni2][kk] = *(const bf16x8*)&s[row * 64 + ((((kk << 2) + quad) ^ sw) << 3)];
  }
}

#define MMQ(qm, half, BF)                                                                \
  _Pragma("unroll") for (int mi2 = 0; mi2 < 2; ++mi2)                                    \
  _Pragma("unroll") for (int ni2 = 0; ni2 < 3; ++ni2)                                    \
  _Pragma("unroll") for (int kk = 0; kk < 2; ++kk)                                       \
      acc[(qm) * 2 + mi2][(half) * 3 + ni2] = __builtin_amdgcn_mfma_f32_16x16x32_bf16(   \
          af[mi2][kk], BF[ni2][kk], acc[(qm) * 2 + mi2][(half) * 3 + ni2], 0, 0, 0);

__global__ __launch_bounds__(512, 2) void gemm_qkv_384(
    const unsigned short* __restrict__ A, const unsigned short* __restrict__ W,
    const float* __restrict__ bias, unsigned short* __restrict__ qk,
    unsigned short* __restrict__ vt) {
  __shared__ __attribute__((aligned(16))) unsigned short sA[2][128 * 64];  // 32KB
  __shared__ __attribute__((aligned(16))) unsigned short sB[2][384 * 64];  // 96KB

  const int t = threadIdx.x;
  const int lane = t & 63;
  const int w = t >> 6;
  const int lm = lane & 15;
  const int quad = lane >> 4;
  const int sw = lm & 7;
  const int wm = (w >> 2) * 64;   // 2 M-groups of 64
  const int wn = (w & 3) * 96;    // 4 N-groups of 96

  const int bid = blockIdx.x;
  const int xcd = bid & 7, lin = bid >> 3;
  const int mt = xcd * 8 + (lin & 7);   // 0..63
  const int nt = lin >> 3;              // 0..7
  const int m0 = mt * 128, n0 = nt * 384;
  const int K = 1024;

  const int srow = t >> 3;
  const int scol = ((t & 7) ^ ((t >> 3) & 7)) << 3;
  const unsigned short* Ab = A + ((size_t)m0 + srow) * K + scol;
  const unsigned short* Wb = W + ((size_t)n0 + srow) * K + scol;

#define QSTG_A(bb, q, kt) gload16(Ab + (size_t)((q) * 64) * K + (kt), &sA[bb][(q) * 4096 + w * 512])
#define QSTG_B(bb, q, kt) gload16(Wb + (size_t)((q) * 64) * K + (kt), &sB[bb][(q) * 4096 + w * 512])

  QSTG_A(0, 0, 0); QSTG_A(0, 1, 0);
  QSTG_B(0, 0, 0); QSTG_B(0, 1, 0); QSTG_B(0, 2, 0);
  QSTG_B(0, 3, 0); QSTG_B(0, 4, 0); QSTG_B(0, 5, 0);
  QSTG_B(1, 0, 64); QSTG_B(1, 1, 64);
  QSTG_A(1, 0, 64); QSTG_A(1, 1, 64);
  QSTG_B(1, 2, 64); QSTG_B(1, 3, 64);
  asm volatile("s_waitcnt vmcnt(6)" ::: "memory");
  BARRIER();

  f32x4 acc[4][6] = {};
  bf16x8 af[2][2], bf0[3][2], bf1[3][2];

#define QGROUP(c, kn1, kn2)                                                           \
  do {                                                                                \
    ld_af2(sA[c], wm + lm, quad, sw, af);                                             \
    ld_bf3(sB[c], wn + lm, quad, sw, bf0);                                            \
    QSTG_B(c ^ 1, 4, kn1);                                                            \
    QSTG_B(c ^ 1, 5, kn1);                                                            \
    BARRIER(); WAITLGKM();                                                            \
    __builtin_amdgcn_s_setprio(1); MMQ(0, 0, bf0); __builtin_amdgcn_s_setprio(0);     \
    BARRIER();                                                                        \
    ld_bf3(sB[c], wn + 48 + lm, quad, sw, bf1);                                       \
    BARRIER(); WAITLGKM();                                                            \
    __builtin_amdgcn_s_setprio(1); MMQ(0, 1, bf1); __builtin_amdgcn_s_setprio(0);     \
    BARRIER();                                                                        \
    ld_af2(sA[c], wm + 32 + lm, quad, sw, af);                                        \
    QSTG_B(c, 0, kn2);                                                                \
    QSTG_B(c, 1, kn2);                                                                \
    BARRIER(); WAITLGKM();                                                            \
    __builtin_amdgcn_s_setprio(1); MMQ(1, 0, bf0); __builtin_amdgcn_s_setprio(0);     \
    BARRIER();                                                                        \
    QSTG_A(c, 0, kn2);                                                                \
    QSTG_A(c, 1, kn2);                                                                \
    QSTG_B(c, 2, kn2);                                                                \
    QSTG_B(c, 3, kn2);                                                                \
    asm volatile("s_waitcnt vmcnt(6)" ::: "memory");                                  \
    BARRIER();                                                                        \
    __builtin_amdgcn_s_setprio(1); MMQ(1, 1, bf1); __builtin_amdgcn_s_setprio(0);     \
    BARRIER();                                                                        \
  } while (0)

  for (int kt = 0; kt < K; kt += 128) {
    const int kn1a = kt + 64;
    const int kn2a = (kt + 128 < K) ? kt + 128 : K - 64;
    const int kn1b = kn2a;
    const int kn2b = (kt + 192 < K) ? kt + 192 : K - 64;
    QGROUP(0, kn1a, kn2a);
    QGROUP(1, kn1b, kn2b);
  }

  asm volatile("s_waitcnt vmcnt(0)" ::: "memory");

#pragma unroll
  for (int mi = 0; mi < 4; ++mi) {
    const int rbase = m0 + wm + mi * 16 + quad * 4;
#pragma unroll
    for (int ni = 0; ni < 6; ++ni) {
      const int col = n0 + wn + ni * 16 + lm;
      const float bv = bias[col];
      float v0 = acc[mi][ni][0] + bv, v1 = acc[mi][ni][1] + bv;
      float v2 = acc[mi][ni][2] + bv, v3 = acc[mi][ni][3] + bv;
      if (col < 2048) {
        qk[(size_t)(rbase + 0) * QK_LD + col] = f2bf(v0);
        qk[(size_t)(rbase + 1) * QK_LD + col] = f2bf(v1);
        qk[(size_t)(rbase + 2) * QK_LD + col] = f2bf(v2);
        qk[(size_t)(rbase + 3) * QK_LD + col] = f2bf(v3);
      } else {  // V: write transposed, 4 consecutive tokens -> one b64
        int c2 = col - 2048;
        int bh = (m0 >> 11) * 16 + (c2 >> 6);
        int hd = c2 & 63;
        int sbase = rbase & 2047;
        uint2 pk = {pkbf(v0, v1), pkbf(v2, v3)};
        *(uint2*)(vt + (size_t)bh * (HD_ * S_) + (size_t)hd * S_ + sbase) = pk;
      }
    }
  }
}

// ---------------- 128x128 gemm (out-proj; proven ~30us @ N=1024) ----------------
__global__ __launch_bounds__(256) void gemm_bt(
    const unsigned short* __restrict__ A, const unsigned short* __restrict__ W,
    const float* __restrict__ bias, void* __restrict__ Cout,
    unsigned short* __restrict__ vt, int M, int N, int K, int mode) {
  __shared__ __attribute__((aligned(16))) unsigned short sA[128 * 32];
  __shared__ __attribute__((aligned(16))) unsigned short sB[128 * 32];
  const int t = threadIdx.x;
  const int lane = t & 63;
  const int w = t >> 6;
  const int lm = lane & 15;
  const int quad = lane >> 4;
  const int m0 = blockIdx.x * 128;
  const int n0 = blockIdx.y * 128;
  const int wm = (w & 1) * 64;
  const int wn = (w >> 1) * 64;

  const int off0 = t * 8, off1 = t * 8 + 2048;
  const int ar0 = off0 >> 5, ac0 = (((off0 >> 3) & 3) ^ ((ar0 >> 1) & 3)) * 8;
  const int ar1 = off1 >> 5, ac1 = (((off1 >> 3) & 3) ^ ((ar1 >> 1) & 3)) * 8;
  const unsigned short* Ag0 = A + (size_t)(m0 + ar0) * K + ac0;
  const unsigned short* Ag1 = A + (size_t)(m0 + ar1) * K + ac1;
  const unsigned short* Wg0 = W + (size_t)(n0 + ar0) * K + ac0;
  const unsigned short* Wg1 = W + (size_t)(n0 + ar1) * K + ac1;
  unsigned short* sA0 = &sA[w * 512];
  unsigned short* sA1 = &sA[2048 + w * 512];
  unsigned short* sB0 = &sB[w * 512];
  unsigned short* sB1 = &sB[2048 + w * 512];

  f32x4 acc[4][4] = {};

  for (int kt = 0; kt < K; kt += 32) {
    gload16(Ag0 + kt, sA0);
    gload16(Ag1 + kt, sA1);
    gload16(Wg0 + kt, sB0);
    gload16(Wg1 + kt, sB1);
    __syncthreads();
    bf16x8 af[4], bf[4];
#pragma unroll
    for (int mi = 0; mi < 4; ++mi) {
      int row = wm + mi * 16 + lm;
      af[mi] = *(const bf16x8*)&sA[row * 32 + ((quad ^ ((row >> 1) & 3)) << 3)];
    }
#pragma unroll
    for (int ni = 0; ni < 4; ++ni) {
      int row = wn + ni * 16 + lm;
      bf[ni] = *(const bf16x8*)&sB[row * 32 + ((quad ^ ((row >> 1) & 3)) << 3)];
    }
#pragma unroll
    for (int mi = 0; mi < 4; ++mi)
#pragma unroll
      for (int ni = 0; ni < 4; ++ni)
        acc[mi][ni] = __builtin_amdgcn_mfma_f32_16x16x32_bf16(af[mi], bf[ni], acc[mi][ni], 0, 0, 0);
    __syncthreads();
  }

#pragma unroll
  for (int mi = 0; mi < 4; ++mi)
#pragma unroll
    for (int ni = 0; ni < 4; ++ni) {
      int col = n0 + wn + ni * 16 + lm;
      float bv = bias[col];
      float v0 = acc[mi][ni][0] + bv, v1 = acc[mi][ni][1] + bv;
      float v2 = acc[mi][ni][2] + bv, v3 = acc[mi][ni][3] + bv;
      int rbase = m0 + wm + mi * 16 + quad * 4;
      if (mode == 0) {
        float* op = (float*)Cout;
        op[(size_t)(rbase + 0) * N + col] = v0;
        op[(size_t)(rbase + 1) * N + col] = v1;
        op[(size_t)(rbase + 2) * N + col] = v2;
        op[(size_t)(rbase + 3) * N + col] = v3;
      } else if (col < 2048) {
        unsigned short* op = (unsigned short*)Cout;
        op[(size_t)(rbase + 0) * QK_LD + col] = f2bf(v0);
        op[(size_t)(rbase + 1) * QK_LD + col] = f2bf(v1);
        op[(size_t)(rbase + 2) * QK_LD + col] = f2bf(v2);
        op[(size_t)(rbase + 3) * QK_LD + col] = f2bf(v3);
      } else {
        int c = col - 2048;
        int bh = (m0 >> 11) * 16 + (c >> 6);
        int hd = c & 63;
        int sbase = (rbase & 2047);
        uint2 pk = {pkbf(v0, v1), pkbf(v2, v3)};
        *(uint2*)(vt + (size_t)bh * (HD_ * S_) + (size_t)hd * S_ + sbase) = pk;
      }
    }
}

// ---------------- flash attention (R13: 8 waves x 32 q-rows, 16 waves/CU) ----------------
__global__ __launch_bounds__(512, 4) void attn_kernel(
    const unsigned short* __restrict__ qk, const unsigned short* __restrict__ vt,
    unsigned short* __restrict__ ab) {
  __shared__ __attribute__((aligned(16))) unsigned short sK[2][64 * 64];
  __shared__ __attribute__((aligned(16))) unsigned short sV[2][64 * 64];  // [hd][n]
  __shared__ __attribute__((aligned(16))) unsigned short sP[8][32 * 64];  // 4KB/wave

  const int t = threadIdx.x;
  const int lane = t & 63;
  const int w = t >> 6;  // 0..7
  const int lm = lane & 15;
  const int quad = lane >> 4;
  const int bh = blockIdx.x & 63;
  const int b = bh >> 4, h = bh & 15;
  const int q0 = (blockIdx.x >> 6) * 256;

  const unsigned short* qg = qk + (size_t)b * S_ * QK_LD + h * HD_;
  const unsigned short* kg = qg + 1024;
  const unsigned short* vg = vt + (size_t)bh * HD_ * S_;

  const int r0 = t >> 3;
  const int c0 = ((t & 7) ^ (r0 & 7)) * 8;

  gload16(kg + (size_t)r0 * QK_LD + c0, &sK[0][w * 512]);
  gload16(vg + (size_t)r0 * S_ + c0, &sV[0][w * 512]);

  bf16x8 qf[2][2];
#pragma unroll
  for (int mi = 0; mi < 2; ++mi) {
    int row = q0 + w * 32 + mi * 16 + lm;
#pragma unroll
    for (int kc = 0; kc < 2; ++kc)
      qf[mi][kc] = *(const bf16x8*)(qg + (size_t)row * QK_LD + kc * 32 + quad * 8);
  }
  __syncthreads();  // K0/V0 staged

  unsigned short* sPw = sP[w];
  const bf16x8 ones = __builtin_bit_cast(bf16x8, (short8)(short)0x3F80);  // 1.0 bf16
  f32x4 o[2][4] = {};
  f32x4 Lacc[2] = {};

  for (int n0 = 0; n0 < S_; n0 += 64) {
    const int cur = (n0 >> 6) & 1, nxt = cur ^ 1;
    if (n0 + 64 < S_) {  // wave-uniform
      gload16(kg + (size_t)(n0 + 64 + r0) * QK_LD + c0, &sK[nxt][w * 512]);
      gload16(vg + (size_t)r0 * S_ + (n0 + 64) + c0, &sV[nxt][w * 512]);
    }

    f32x4 s[2][4] = {};
#pragma unroll
    for (int kc = 0; kc < 2; ++kc)
#pragma unroll
      for (int nb = 0; nb < 4; ++nb) {
        int row = nb * 16 + lm;
        bf16x8 kf = *(const bf16x8*)&sK[cur][row * 64 + (((kc * 4 + quad) ^ (row & 7)) << 3)];
#pragma unroll
        for (int mi = 0; mi < 2; ++mi)
          s[mi][nb] = __builtin_amdgcn_mfma_f32_16x16x32_bf16(kf, qf[mi][kc], s[mi][nb], 0, 0, 0);
      }

#pragma unroll
    for (int mi = 0; mi < 2; ++mi) {
      int prow = mi * 16 + lm;
      char* rowp = (char*)sPw + prow * 128;
#pragma unroll
      for (int nb = 0; nb < 4; ++nb) {
        const f32x4& sv = s[mi][nb];
        uint2 pk = {pkbf(__builtin_amdgcn_exp2f(sv[0]), __builtin_amdgcn_exp2f(sv[1])),
                    pkbf(__builtin_amdgcn_exp2f(sv[2]), __builtin_amdgcn_exp2f(sv[3]))};
        int c16 = (nb * 2 + (quad >> 1)) ^ (prow & 7);
        *(uint2*)(rowp + (c16 << 4) + ((quad & 1) << 3)) = pk;
      }
    }

#pragma unroll
    for (int kc = 0; kc < 2; ++kc) {
      bf16x8 pf[2];
#pragma unroll
      for (int mi = 0; mi < 2; ++mi) {
        int prow = mi * 16 + lm;
        pf[mi] = *(const bf16x8*)&sPw[prow * 64 + (((kc * 4 + quad) ^ (prow & 7)) << 3)];
        Lacc[mi] = __builtin_amdgcn_mfma_f32_16x16x32_bf16(pf[mi], ones, Lacc[mi], 0, 0, 0);
      }
#pragma unroll
      for (int nf = 0; nf < 4; ++nf) {
        int row = nf * 16 + lm;
        bf16x8 vf = *(const bf16x8*)&sV[cur][row * 64 + (((kc * 4 + quad) ^ (row & 7)) << 3)];
#pragma unroll
        for (int mi = 0; mi < 2; ++mi)
          o[mi][nf] = __builtin_amdgcn_mfma_f32_16x16x32_bf16(pf[mi], vf, o[mi][nf], 0, 0, 0);
      }
    }
    __syncthreads();
  }

#pragma unroll
  for (int mi = 0; mi < 2; ++mi)
#pragma unroll
    for (int r = 0; r < 4; ++r) {
      float rinv = 1.0f / Lacc[mi][r];
      int row = q0 + w * 32 + mi * 16 + quad * 4 + r;
#pragma unroll
      for (int nf = 0; nf < 4; ++nf) {
        int col = h * HD_ + nf * 16 + lm;
        ab[(size_t)(b * S_ + row) * D_ + col] = f2bf(o[mi][nf][r] * rinv);
      }
    }
}

extern "C" void kernel_launch(void* const* d_in, const int* in_sizes, int n_in,
                              void* d_out, int out_size, void* d_ws, size_t ws_size,
                              hipStream_t stream) {
  const float* x = (const float*)d_in[0];
  const float* Wq = (const float*)d_in[1];
  const float* bq = (const float*)d_in[2];
  const float* Wk = (const float*)d_in[3];
  const float* bk = (const float*)d_in[4];
  const float* Wv = (const float*)d_in[5];
  const float* bv = (const float*)d_in[6];
  const float* Wo = (const float*)d_in[7];
  const float* bo = (const float*)d_in[8];
  float* out = (float*)d_out;

  const size_t E = (size_t)B_ * S_ * D_;   // 8388608
  const size_t WE = (size_t)D_ * D_;       // 1048576
  unsigned short* xb = (unsigned short*)d_ws;
  unsigned short* wcat = xb + E;
  unsigned short* wob = wcat + 3 * WE;
  float* bcat = (float*)(wcat + 4 * WE);
  unsigned short* qkb = (unsigned short*)(bcat + 4096);
  unsigned short* vtb = qkb + (size_t)B_ * S_ * QK_LD;
  unsigned short* abuf = xb;  // reuse: x consumed by QKV gemm before attention writes

  cvt_all<<<dim3(6145), 256, 0, stream>>>(x, Wq, Wk, Wv, Wo, bq, bk, bv, xb, wcat, bcat);

  gemm_qkv_384<<<dim3(512), 512, 0, stream>>>(xb, wcat, bcat, qkb, vtb);
  attn_kernel<<<dim3(512), 512, 0, stream>>>(qkb, vtb, abuf);
  gemm_bt<<<dim3((B_ * S_) / 128, D_ / 128), 256, 0, stream>>>(
      abuf, wob, bo, out, nullptr, B_ * S_, D_, D_, 0);
}